// Round 5
// baseline (455.678 us; speedup 1.0000x reference)
//
#include <hip/hip_runtime.h>
#include <math.h>

#define Bq 2
#define Lq 2048
#define DIMq 768
#define NHq 12
#define HDq 64

typedef __attribute__((ext_vector_type(8))) short short8;
typedef __attribute__((ext_vector_type(4))) short short4v;
typedef __attribute__((ext_vector_type(4))) float float4v;

// async global->LDS, 16 B per lane; LDS dest = wave-uniform base + lane*16
#define GL2LDS(g, l) __builtin_amdgcn_global_load_lds( \
    (const __attribute__((address_space(1))) unsigned int*)(g), \
    (__attribute__((address_space(3))) unsigned int*)(l), 16, 0, 0)

static __device__ __forceinline__ short f2bf(float f) {
    union { float f; unsigned u; } v; v.f = f;
    unsigned r = (v.u + 0x7FFF + ((v.u >> 16) & 1)) >> 16;   // RNE
    return (short)r;
}
static __device__ __forceinline__ unsigned pack2bf(float a, float b) {
    return (unsigned)(unsigned short)f2bf(a) | ((unsigned)(unsigned short)f2bf(b) << 16);
}

// ---------------------------------------------------------------------------
// fp32 -> bf16 for x and the four weights (wq/wk/wv written contiguously).
// ---------------------------------------------------------------------------
__global__ __launch_bounds__(256)
void to_bf16(const float* __restrict__ x,  const float* __restrict__ wq,
             const float* __restrict__ wk, const float* __restrict__ wv,
             const float* __restrict__ wo,
             short* __restrict__ xb, short* __restrict__ wqb,
             short* __restrict__ wkb, short* __restrict__ wvb,
             short* __restrict__ wob)
{
    int blk = blockIdx.x;
    const float* s; short* d; int off;
    if      (blk <  768) { s = x;  d = xb;  off = blk * 1024; }
    else if (blk <  912) { s = wq; d = wqb; off = (blk -  768) * 1024; }
    else if (blk < 1056) { s = wk; d = wkb; off = (blk -  912) * 1024; }
    else if (blk < 1200) { s = wv; d = wvb; off = (blk - 1056) * 1024; }
    else                 { s = wo; d = wob; off = (blk - 1200) * 1024; }
    const float4* s4 = (const float4*)s;
    short4v* d4 = (short4v*)d;
#pragma unroll
    for (int i = 0; i < 4; ++i) {
        int idx = off + threadIdx.x + i * 256;
        float4 v = s4[idx];
        short4v o;
        o[0] = f2bf(v.x); o[1] = f2bf(v.y); o[2] = f2bf(v.z); o[3] = f2bf(v.w);
        d4[idx] = o;
    }
}

// ---------------------------------------------------------------------------
// m97-style bf16 GEMM: C = A @ W^T.  128x128 tile, BK=64, 4 waves (2x2 of
// 64x64), global_load_lds(16B) staging, XOR chunk swizzle.
// mode 0: OutF fp32 [M][768].
// mode 1: N=2304 fused QKV.  Q -> [bh][l][hd]; K -> pre-swizzled LDS-image
//   tiles.  V blocks (n0>=1536) run the K-loop with SWAPPED mfma operands so
//   the accumulator holds V^T -> Vtg stores are 16B-coalesced.
// ---------------------------------------------------------------------------
__global__ __launch_bounds__(256, 3)
void gemm128(const short* __restrict__ A, const short* __restrict__ W,
             short* __restrict__ Qg, short* __restrict__ Ktg,
             short* __restrict__ Vtg, float* __restrict__ OutF, int mode)
{
    __shared__ __align__(16) short As[128 * 64];
    __shared__ __align__(16) short Bs[128 * 64];
    const int tid = threadIdx.x;
    const int wave = tid >> 6, lane = tid & 63;
    const int col = lane & 15, quad = lane >> 4;
    const int m0 = blockIdx.y * 128, n0 = blockIdx.x * 128;
    const int mw = (wave & 1) * 64, nw = (wave >> 1) * 64;
    const int lr8 = lane >> 3, lc8 = lane & 7;
    const bool trn = (mode == 1) && (n0 >= 1536);   // V-projection: transposed

    float4v acc[4][4];
#pragma unroll
    for (int it = 0; it < 4; ++it)
#pragma unroll
        for (int nt = 0; nt < 4; ++nt) acc[it][nt] = (float4v){0.f, 0.f, 0.f, 0.f};

    for (int k0 = 0; k0 < DIMq; k0 += 64) {
        if (k0) __syncthreads();
#pragma unroll
        for (int i = 0; i < 4; ++i) {
            int issue = wave * 4 + i;
            int r = issue * 8 + lr8;            // tile row 0..127
            int c = lc8 ^ (r & 7);              // swizzled global chunk
            GL2LDS(A + (size_t)(m0 + r) * DIMq + k0 + c * 8, &As[issue * 512]);
            GL2LDS(W + (size_t)(n0 + r) * DIMq + k0 + c * 8, &Bs[issue * 512]);
        }
        __syncthreads();
#pragma unroll
        for (int kk = 0; kk < 2; ++kk) {
            short8 a[4], bfr[4];
#pragma unroll
            for (int it = 0; it < 4; ++it) {
                int r = mw + it * 16 + col;
                a[it] = *(const short8*)&As[r * 64 + (((kk * 4 + quad) ^ (r & 7)) * 8)];
            }
#pragma unroll
            for (int nt = 0; nt < 4; ++nt) {
                int r = nw + nt * 16 + col;
                bfr[nt] = *(const short8*)&Bs[r * 64 + (((kk * 4 + quad) ^ (r & 7)) * 8)];
            }
            if (trn) {
#pragma unroll
                for (int it = 0; it < 4; ++it)
#pragma unroll
                    for (int nt = 0; nt < 4; ++nt)
                        acc[it][nt] = __builtin_amdgcn_mfma_f32_16x16x32_bf16(
                            bfr[nt], a[it], acc[it][nt], 0, 0, 0);
            } else {
#pragma unroll
                for (int it = 0; it < 4; ++it)
#pragma unroll
                    for (int nt = 0; nt < 4; ++nt)
                        acc[it][nt] = __builtin_amdgcn_mfma_f32_16x16x32_bf16(
                            a[it], bfr[nt], acc[it][nt], 0, 0, 0);
            }
        }
    }

    if (mode == 0) {
#pragma unroll
        for (int it = 0; it < 4; ++it)
#pragma unroll
            for (int reg = 0; reg < 4; ++reg) {
                float* orow = OutF + (size_t)(m0 + mw + it * 16 + quad * 4 + reg) * DIMq
                            + n0 + nw + col;
#pragma unroll
                for (int nt = 0; nt < 4; ++nt) orow[nt * 16] = acc[it][nt][reg];
            }
    } else if (!trn) {
        const int mat = n0 / 768;                 // 0 = Q, 1 = K
        const int nbase = n0 - mat * 768 + nw;
#pragma unroll
        for (int it = 0; it < 4; ++it)
#pragma unroll
            for (int reg = 0; reg < 4; ++reg) {
                int m = m0 + mw + it * 16 + quad * 4 + reg;
                int bb = m >> 11, l = m & 2047;
#pragma unroll
                for (int nt = 0; nt < 4; ++nt) {
                    int nloc = nbase + nt * 16 + col;
                    int hh = nloc >> 6, c = nloc & 63;
                    size_t bh = (size_t)(bb * NHq + hh);
                    short v = f2bf(acc[it][nt][reg]);
                    if (mat == 0) {
                        Qg[(bh * Lq + l) * HDq + c] = v;
                    } else {
                        // K tile image: [bh][kt32][key32][hd-chunk ^ (key&7)]
                        Ktg[(bh * 64 + (l >> 5)) * 2048 + (l & 31) * 64
                            + (((c >> 3) ^ (l & 7)) * 8) + (c & 7)] = v;
                    }
                }
            }
    } else {
        // acc[it][nt] holds V^T: row n (v-dim) = nbase+nt*16+quad*4+reg,
        // col = token m0+mw+it*16+col  ->  coalesced along tokens.
        const int nbase = n0 - 1536 + nw;
#pragma unroll
        for (int it = 0; it < 4; ++it)
#pragma unroll
            for (int nt = 0; nt < 4; ++nt)
#pragma unroll
                for (int reg = 0; reg < 4; ++reg) {
                    int n = nbase + nt * 16 + quad * 4 + reg;   // 0..767
                    int hh = n >> 6, c = n & 63;
                    int t = m0 + mw + it * 16 + col;
                    int bb = t >> 11, l = t & 2047;
                    size_t bh = (size_t)(bb * NHq + hh);
                    // V^T tile image: [bh][kt32][hd][key-chunk ^ (hd&3)]
                    Vtg[(bh * 64 + (l >> 5)) * 2048 + c * 32
                        + ((((l & 31) >> 3) ^ (c & 3)) * 8) + (l & 7)]
                        = f2bf(acc[it][nt][reg]);
                }
    }
}

// ---------------------------------------------------------------------------
// Flash attention, S^T/O^T scheme.  64 q-rows/block, K-tiles of 32 keys.
// S^T = K @ Q^T (A=K frag, B=Q frag): C row = key, col = qrow -> each lane's
// 8 scores belong to ONE q-row; softmax = in-lane tree + 2 shfl steps; m/l
// scalar per lane.  Bias [qrow][4 keys] = per-lane float4, double-buffered in
// registers, used as the MFMA accumulator init.  O^T = V^T @ P^T.  K/V via
// async GL2LDS of pre-swizzled images, double-buffered; 1 barrier/iter.
// ---------------------------------------------------------------------------
__global__ __launch_bounds__(256, 4)
void attn_fwd3(const short* __restrict__ Qg, const short* __restrict__ Ktg,
               const short* __restrict__ Vtg, const float* __restrict__ pos_bias,
               const int* __restrict__ mask, short* __restrict__ AO)
{
    __shared__ __align__(16) short Ks[2][2048];   // [key32][hd64] swizzled
    __shared__ __align__(16) short Vt[2][2048];   // [hd64][key32] swizzled
    __shared__ __align__(16) float mAll[Lq];      // 0 / -1e38 per key
    __shared__ __align__(16) short Ps[4][16][48]; // [wave][qrow][key32], pad 48

    const int qt = blockIdx.x, h = blockIdx.y, b = blockIdx.z;
    const int bh = b * NHq + h;
    const int tid = threadIdx.x;
    const int wave = tid >> 6, lane = tid & 63;
    const int col = lane & 15, quad = lane >> 4;

    const short* Kb = Ktg + (size_t)bh * 64 * 2048;
    const short* Vb = Vtg + (size_t)bh * 64 * 2048;
    const int* mk = mask + b * Lq;

    for (int i = tid; i < Lq; i += 256) mAll[i] = mk[i] ? 0.0f : -1e38f;

    // Q B-frags (qrow = qt*64 + wave*16 + col)
    const short* qrow = Qg + ((size_t)bh * Lq + qt * 64 + wave * 16 + col) * HDq;
    const short8 qa0 = *(const short8*)&qrow[quad * 8];
    const short8 qa1 = *(const short8*)&qrow[32 + quad * 8];

    // bias row for this lane's q-row; element (nt, kt): float4 of 4 keys
    const float* Bb = pos_bias + (size_t)h * Lq * Lq
                    + (size_t)(qt * 64 + wave * 16 + col) * Lq + quad * 4;

    auto stage = [&](int kt, int buf) {
        GL2LDS(Kb + (size_t)kt * 2048 + wave * 512 + lane * 8, &Ks[buf][wave * 512]);
        GL2LDS(Vb + (size_t)kt * 2048 + wave * 512 + lane * 8, &Vt[buf][wave * 512]);
    };
    float4v bias_cur[2], bias_nxt[2];
    auto pre_bias = [&](int kt, float4v (&bb)[2]) {
#pragma unroll
        for (int nt = 0; nt < 2; ++nt)
            bb[nt] = *(const float4v*)&Bb[kt * 32 + nt * 16];
    };

    stage(0, 0);
    pre_bias(0, bias_cur);

    float4v O[4];
#pragma unroll
    for (int nt = 0; nt < 4; ++nt) O[nt] = (float4v){0.f, 0.f, 0.f, 0.f};
    float m_run = -1e37f, l_run = 0.f;

    __syncthreads();   // tile 0 + mAll visible

    for (int kt = 0; kt < 64; ++kt) {
        const int cur = kt & 1;
        if (kt + 1 < 64) { stage(kt + 1, cur ^ 1); pre_bias(kt + 1, bias_nxt); }

        // --- S^T = K @ Q^T, accumulator seeded with bias+mask ---
        float4v S[2];
#pragma unroll
        for (int nt = 0; nt < 2; ++nt) {
            float4v mb = *(const float4v*)&mAll[kt * 32 + nt * 16 + quad * 4];
            S[nt] = bias_cur[nt] + mb;
            int key = nt * 16 + col;
            short8 kb0 = *(const short8*)&Ks[cur][key * 64 + ((quad ^ (key & 7)) * 8)];
            short8 kb1 = *(const short8*)&Ks[cur][key * 64 + (((4 + quad) ^ (key & 7)) * 8)];
            S[nt] = __builtin_amdgcn_mfma_f32_16x16x32_bf16(kb0, qa0, S[nt], 0, 0, 0);
            S[nt] = __builtin_amdgcn_mfma_f32_16x16x32_bf16(kb1, qa1, S[nt], 0, 0, 0);
        }

        // --- online softmax: in-lane tree + 2 shfl steps ---
        float tm = fmaxf(fmaxf(fmaxf(S[0][0], S[0][1]), fmaxf(S[0][2], S[0][3])),
                         fmaxf(fmaxf(S[1][0], S[1][1]), fmaxf(S[1][2], S[1][3])));
        tm = fmaxf(tm, __shfl_xor(tm, 16, 64));
        tm = fmaxf(tm, __shfl_xor(tm, 32, 64));
        float mnew = fmaxf(m_run, tm);
        float alpha = __expf(m_run - mnew);
        m_run = mnew;
        float p[2][4], ps = 0.f;
#pragma unroll
        for (int nt = 0; nt < 2; ++nt)
#pragma unroll
            for (int reg = 0; reg < 4; ++reg) {
                float pv = __expf(S[nt][reg] - mnew);
                p[nt][reg] = pv;
                ps += pv;
            }
        ps += __shfl_xor(ps, 16, 64);
        ps += __shfl_xor(ps, 32, 64);
        l_run = l_run * alpha + ps;

        // --- P^T -> LDS (packed b32 writes), rescale O ---
#pragma unroll
        for (int nt = 0; nt < 2; ++nt) {
            *(unsigned*)&Ps[wave][col][nt * 16 + quad * 4]     = pack2bf(p[nt][0], p[nt][1]);
            *(unsigned*)&Ps[wave][col][nt * 16 + quad * 4 + 2] = pack2bf(p[nt][2], p[nt][3]);
        }
#pragma unroll
        for (int nt = 0; nt < 4; ++nt)
#pragma unroll
            for (int reg = 0; reg < 4; ++reg)
                O[nt][reg] *= alpha;
        asm volatile("s_waitcnt lgkmcnt(0)" ::: "memory");   // wave-local Ps ready

        // --- O^T += V^T @ P^T ---
        short8 pa = *(const short8*)&Ps[wave][col][quad * 8];
#pragma unroll
        for (int nt = 0; nt < 4; ++nt) {
            int hd = nt * 16 + col;
            short8 vb = *(const short8*)&Vt[cur][hd * 32 + ((quad ^ (hd & 3)) * 8)];
            O[nt] = __builtin_amdgcn_mfma_f32_16x16x32_bf16(vb, pa, O[nt], 0, 0, 0);
        }

#pragma unroll
        for (int nt = 0; nt < 2; ++nt) bias_cur[nt] = bias_nxt[nt];
        __syncthreads();   // single barrier: prefetch landed, cur buffer free
    }

    // --- epilogue: O^T lane (quad,col) -> AO[b][qrow][h*64 + nt*16+quad*4+reg]
    float inv = 1.0f / l_run;
    short* ao = AO + ((size_t)b * Lq + qt * 64 + wave * 16 + col) * DIMq + h * HDq;
#pragma unroll
    for (int nt = 0; nt < 4; ++nt) {
        short4v v4;
#pragma unroll
        for (int reg = 0; reg < 4; ++reg) v4[reg] = f2bf(O[nt][reg] * inv);
        *(short4v*)&ao[nt * 16 + quad * 4] = v4;
    }
}

// ---------------------------------------------------------------------------
extern "C" void kernel_launch(void* const* d_in, const int* in_sizes, int n_in,
                              void* d_out, int out_size, void* d_ws, size_t ws_size,
                              hipStream_t stream) {
    const float* x        = (const float*)d_in[0];
    const float* pos_bias = (const float*)d_in[1];
    const float* Wq       = (const float*)d_in[2];
    const float* Wk       = (const float*)d_in[3];
    const float* Wv       = (const float*)d_in[4];
    const float* Wo       = (const float*)d_in[5];
    const int*   mask     = (const int*)d_in[6];
    float* out = (float*)d_out;

    const size_t nX = (size_t)Bq * Lq * DIMq;   // 3,145,728
    const size_t nW = (size_t)DIMq * DIMq;      //   589,824
    short* xb   = (short*)d_ws;
    short* wqkv = xb + nX;                      // wq|wk|wv contiguous (N=2304)
    short* wob  = wqkv + 3 * nW;
    short* Qg   = wob + nW;                     // [bh][l][hd]
    short* Ktg  = Qg + nX;                      // pre-swizzled K tiles
    short* Vtg  = Ktg + nX;                     // pre-swizzled V^T tiles
    short* AOb  = Vtg + nX;                     // [B][L][DIM] bf16

    dim3 blk(256);
    hipLaunchKernelGGL(to_bf16, dim3(1344), blk, 0, stream,
                       x, Wq, Wk, Wv, Wo, xb, wqkv, wqkv + nW, wqkv + 2 * nW, wob);

    hipLaunchKernelGGL(gemm128, dim3(2304 / 128, (Bq * Lq) / 128), blk, 0, stream,
                       xb, wqkv, Qg, Ktg, Vtg, (float*)nullptr, 1);

    hipLaunchKernelGGL(attn_fwd3, dim3(Lq / 64, NHq, Bq), blk, 0, stream,
                       Qg, Ktg, Vtg, pos_bias, mask, AOb);

    hipLaunchKernelGGL(gemm128, dim3(DIMq / 128, (Bq * Lq) / 128), blk, 0, stream,
                       AOb, wob, (short*)nullptr, (short*)nullptr,
                       (short*)nullptr, out, 0);
}